// Round 1
// baseline (348.558 us; speedup 1.0000x reference)
//
#include <hip/hip_runtime.h>
#include <hip/hip_cooperative_groups.h>
#include <math.h>

#define F 128
#define FIX_SCALE 16777216.0f          // 2^24
#define FIX_INV   (1.0f / 16777216.0f)
#define CNT_SHIFT 40
#define DEG_MASK  ((1ULL << 40) - 1)

using bf16x8 = __attribute__((ext_vector_type(8))) short;
using f32x4  = __attribute__((ext_vector_type(4))) float;

// ---------- helpers ----------
__device__ inline int read_idx(const int* ei, long long elem, int i64) {
    return i64 ? (int)((const long long*)ei)[elem] : ei[elem];
}
__device__ inline unsigned int f2bf_rn(float f) {   // fp32 -> bf16 bits, round-nearest-even
    unsigned int b = __float_as_uint(f);
    return (b + 0x7FFFu + ((b >> 16) & 1u)) >> 16;
}
__device__ inline float bflo(unsigned int u) { return __uint_as_float(u << 16); }
__device__ inline float bfhi(unsigned int u) { return __uint_as_float(u & 0xFFFF0000u); }

// ---------- K1: zero packed counters, detect index dtype ----------
__global__ void k_init(unsigned long long* packed, int* flag, const int* ei, int N) {
    int i = blockIdx.x * blockDim.x + threadIdx.x;
    if (i < N) packed[i] = 0ULL;
    if (i == 0) {
        int i64 = 1;
        for (int j = 0; j < 32; ++j) if (ei[2 * j + 1] != 0) { i64 = 0; break; }
        *flag = i64;
    }
}

// ---------- K2: count+deg atomics (blocks [0,cntBlocks)) + GRU evolve (blocks [cntBlocks,cntBlocks+F)) ----------
__global__ __launch_bounds__(256) void k_count_evolve(
        const int* __restrict__ ei, const float* __restrict__ ew,
        unsigned long long* __restrict__ packed, int* __restrict__ pos,
        const int* __restrict__ flag, int E, int cntBlocks,
        const float* __restrict__ W0, const float* __restrict__ Wih,
        const float* __restrict__ Whh, const float* __restrict__ bih,
        const float* __restrict__ bhh,
        unsigned short* __restrict__ Wth, unsigned short* __restrict__ Wtl) {
    __shared__ __align__(16) float w0row[F];
    if ((int)blockIdx.x < cntBlocks) {
        int e = blockIdx.x * 256 + threadIdx.x;
        if (e >= E) return;
        int i64 = *flag;
        int c = read_idx(ei, (long long)E + e, i64);
        unsigned long long u = (1ULL << CNT_SHIFT) |
                               (unsigned long long)(ew[e] * FIX_SCALE + 0.5f);
        unsigned long long old = atomicAdd(&packed[c], u);
        pos[e] = (int)(old >> CNT_SHIFT);
        return;
    }
    // ---- evolve path: one block per row i of W0; Wt[n][k] split-bf16 ----
    int i = blockIdx.x - cntBlocks;   // k index (row of W)
    int j = threadIdx.x;              // n index (col of W)
    if (j < F) w0row[j] = W0[i * F + j];
    __syncthreads();
    if (j >= F) return;
    float air = 0, aiz = 0, ain = 0, ahr = 0, ahz = 0, ahn = 0;
    const float* ir_p = Wih + (size_t)j * F;
    const float* iz_p = Wih + (size_t)(j + F) * F;
    const float* in_p = Wih + (size_t)(j + 2 * F) * F;
    const float* hr_p = Whh + (size_t)j * F;
    const float* hz_p = Whh + (size_t)(j + F) * F;
    const float* hn_p = Whh + (size_t)(j + 2 * F) * F;
    for (int k = 0; k < F; k += 4) {
        float4 w0 = *(const float4*)&w0row[k];
        float4 a;
        a = *(const float4*)&ir_p[k]; air += w0.x*a.x + w0.y*a.y + w0.z*a.z + w0.w*a.w;
        a = *(const float4*)&iz_p[k]; aiz += w0.x*a.x + w0.y*a.y + w0.z*a.z + w0.w*a.w;
        a = *(const float4*)&in_p[k]; ain += w0.x*a.x + w0.y*a.y + w0.z*a.z + w0.w*a.w;
        a = *(const float4*)&hr_p[k]; ahr += w0.x*a.x + w0.y*a.y + w0.z*a.z + w0.w*a.w;
        a = *(const float4*)&hz_p[k]; ahz += w0.x*a.x + w0.y*a.y + w0.z*a.z + w0.w*a.w;
        a = *(const float4*)&hn_p[k]; ahn += w0.x*a.x + w0.y*a.y + w0.z*a.z + w0.w*a.w;
    }
    air += bih[j];         ahr += bhh[j];
    aiz += bih[j + F];     ahz += bhh[j + F];
    ain += bih[j + 2*F];   ahn += bhh[j + 2*F];
    float r = 1.0f / (1.0f + expf(-(air + ahr)));
    float z = 1.0f / (1.0f + expf(-(aiz + ahz)));
    float n = tanhf(ain + r * ahn);
    float w = (1.0f - z) * n + z * w0row[j];
    unsigned int hb = f2bf_rn(w);
    float whi = __uint_as_float(hb << 16);
    unsigned int lb = f2bf_rn(w - whi);
    Wth[j * F + i] = (unsigned short)hb;
    Wtl[j * F + i] = (unsigned short)lb;
}

// ---------- K3: cooperative scan: off = exclusive CSR offsets; dinv = rsqrt(1 + deg) ----------
__global__ __launch_bounds__(256) void k_scan(const unsigned long long* __restrict__ packed,
                       int* __restrict__ bsum, int* __restrict__ off,
                       float* __restrict__ dinv, int N, int E, int nblk) {
    cooperative_groups::grid_group grid = cooperative_groups::this_grid();
    __shared__ int sdata[256];
    int t = threadIdx.x, b = blockIdx.x;
    int i = b * 256 + t;
    unsigned long long p = (i < N) ? packed[i] : 0ULL;
    int v = (int)(p >> CNT_SHIFT);
    sdata[t] = v;
    __syncthreads();
    #pragma unroll
    for (int s = 1; s < 256; s <<= 1) {
        int add = (t >= s) ? sdata[t - s] : 0;
        __syncthreads();
        sdata[t] += add;
        __syncthreads();
    }
    int incl = sdata[t];
    if (t == 255) bsum[b] = incl;
    __threadfence();
    grid.sync();
    if (b == 0) {
        int run = 0;
        for (int base = 0; base < nblk; base += 256) {
            int idx = base + t;
            int bv = (idx < nblk) ? bsum[idx] : 0;
            __syncthreads();
            sdata[t] = bv;
            __syncthreads();
            #pragma unroll
            for (int s = 1; s < 256; s <<= 1) {
                int add = (t >= s) ? sdata[t - s] : 0;
                __syncthreads();
                sdata[t] += add;
                __syncthreads();
            }
            if (idx < nblk) bsum[idx] = run + sdata[t] - bv;  // exclusive
            run += sdata[255];
            __syncthreads();
        }
        __threadfence();
    }
    grid.sync();
    if (i < N) {
        off[i] = bsum[b] + incl - v;  // exclusive
        float deg = 1.0f + (float)(p & DEG_MASK) * FIX_INV;  // +1 self-loop
        dinv[i] = rsqrtf(deg);
        if (i == N - 1) off[N] = E;
    }
}

// ---------- K4: edge placement (blocks [0,placeBlocks)) + xs cast (rest) ----------
__global__ __launch_bounds__(256) void k_place_cast(
        const int* __restrict__ ei, const float* __restrict__ ew,
        const int* __restrict__ off, const int* __restrict__ pos,
        int2* __restrict__ ep, const int* __restrict__ flag, int E, int placeBlocks,
        const float2* __restrict__ x2, const float* __restrict__ dinv,
        unsigned int* __restrict__ xs, int M) {
    if ((int)blockIdx.x < placeBlocks) {
        int e = blockIdx.x * 256 + threadIdx.x;
        if (e >= E) return;
        int i64 = *flag;
        int r = read_idx(ei, e, i64);
        int c = read_idx(ei, (long long)E + e, i64);
        ep[off[c] + pos[e]] = make_int2(r, __float_as_int(ew[e]));
    } else {
        int id = ((int)blockIdx.x - placeBlocks) * 256 + threadIdx.x;
        if (id >= M) return;
        float di = dinv[id >> 6];
        float2 v = x2[id];
        xs[id] = f2bf_rn(di * v.x) | (f2bf_rn(di * v.y) << 16);
    }
}

// ---------- K5: fused aggregation + MFMA GEMM + projection ----------
// Block = 64 nodes. Each wave aggregates its 16 rows directly into the LDS A-tile,
// then the block runs relu(A@W) @ Wlin^T + blin.
__global__ __launch_bounds__(256) void k_agg_gemm(
        const uint4* __restrict__ xs4, const int* __restrict__ off,
        const int2* __restrict__ ep, const float* __restrict__ dinv,
        const unsigned short* __restrict__ Wth, const unsigned short* __restrict__ Wtl,
        const float* __restrict__ Wlin, const float* __restrict__ blin,
        float* __restrict__ out, int N) {
    __shared__ __align__(16) unsigned int At[64 * 68];  // 64 rows bf16x128, stride padded 68 uints
    __shared__ __align__(16) float WlinL[8 * F];
    int t = threadIdx.x;
    int wave = t >> 6, lane = t & 63;
    int row0 = blockIdx.x * 64;
    *(float4*)&WlinL[t * 4] = *(const float4*)&Wlin[t * 4];   // 1024 floats

    int g = lane >> 4, sl = lane & 15;
    // ---- aggregation phase: wave handles rows [wave*16, wave*16+16) ----
    for (int sub = 0; sub < 16; ++sub) {
        int rr = wave * 16 + sub;
        int c = row0 + rr;
        if (c < N) {
            float a0[8] = {0,0,0,0,0,0,0,0}, a1[8] = {0,0,0,0,0,0,0,0};
            if (g == 0) {   // self-loop (raw weight 1)
                uint4 vv = xs4[(size_t)c * 16 + sl];
                a0[0] = bflo(vv.x); a0[1] = bfhi(vv.x);
                a0[2] = bflo(vv.y); a0[3] = bfhi(vv.y);
                a0[4] = bflo(vv.z); a0[5] = bfhi(vv.z);
                a0[6] = bflo(vv.w); a0[7] = bfhi(vv.w);
            }
            int start = off[c], end = off[c + 1];
            for (int k = start; k < end; k += 8) {
                int iA = k + g, iB = k + g + 4;
                bool okA = iA < end, okB = iB < end;
                int2 eA, eB;
                if (okA) eA = ep[iA];
                if (okB) eB = ep[iB];
                if (okA) {
                    uint4 vv = xs4[(size_t)eA.x * 16 + sl];
                    float w = __int_as_float(eA.y);
                    a0[0] += w * bflo(vv.x); a0[1] += w * bfhi(vv.x);
                    a0[2] += w * bflo(vv.y); a0[3] += w * bfhi(vv.y);
                    a0[4] += w * bflo(vv.z); a0[5] += w * bfhi(vv.z);
                    a0[6] += w * bflo(vv.w); a0[7] += w * bfhi(vv.w);
                }
                if (okB) {
                    uint4 vv = xs4[(size_t)eB.x * 16 + sl];
                    float w = __int_as_float(eB.y);
                    a1[0] += w * bflo(vv.x); a1[1] += w * bfhi(vv.x);
                    a1[2] += w * bflo(vv.y); a1[3] += w * bfhi(vv.y);
                    a1[4] += w * bflo(vv.z); a1[5] += w * bfhi(vv.z);
                    a1[6] += w * bflo(vv.w); a1[7] += w * bfhi(vv.w);
                }
            }
            #pragma unroll
            for (int f = 0; f < 8; ++f) {
                float v2 = a0[f] + a1[f];
                v2 += __shfl_xor(v2, 16, 64);
                v2 += __shfl_xor(v2, 32, 64);
                a0[f] = v2;
            }
            if (lane < 16) {
                float di = dinv[c];
                uint4 o;
                o.x = f2bf_rn(di * a0[0]) | (f2bf_rn(di * a0[1]) << 16);
                o.y = f2bf_rn(di * a0[2]) | (f2bf_rn(di * a0[3]) << 16);
                o.z = f2bf_rn(di * a0[4]) | (f2bf_rn(di * a0[5]) << 16);
                o.w = f2bf_rn(di * a0[6]) | (f2bf_rn(di * a0[7]) << 16);
                *(uint4*)&At[rr * 68 + sl * 4] = o;
            }
        } else if (lane < 16) {
            *(uint4*)&At[rr * 68 + sl * 4] = make_uint4(0u, 0u, 0u, 0u);
        }
    }
    __syncthreads();

    // ---- GEMM phase ----
    int q = g;                            // lane >> 4
    const unsigned short* Ash = (const unsigned short*)At;
    int mrow = wave * 16 + sl;            // A-row within tile (m = lane&15)
    f32x4 acc[8];
    #pragma unroll
    for (int nt = 0; nt < 8; ++nt) acc[nt] = (f32x4){0.f, 0.f, 0.f, 0.f};
    #pragma unroll
    for (int ko = 0; ko < 4; ++ko) {
        bf16x8 a = *(const bf16x8*)&Ash[mrow * 136 + ko * 32 + q * 8];
        #pragma unroll
        for (int nt = 0; nt < 8; ++nt) {
            int boff = (nt * 16 + sl) * F + ko * 32 + q * 8;
            bf16x8 bh = *(const bf16x8*)&Wth[boff];
            bf16x8 bl = *(const bf16x8*)&Wtl[boff];
            acc[nt] = __builtin_amdgcn_mfma_f32_16x16x32_bf16(a, bh, acc[nt], 0, 0, 0);
            acc[nt] = __builtin_amdgcn_mfma_f32_16x16x32_bf16(a, bl, acc[nt], 0, 0, 0);
        }
    }
    // relu (C layout: row = q*4+reg, col = nt*16+sl)
    #pragma unroll
    for (int nt = 0; nt < 8; ++nt)
        #pragma unroll
        for (int r = 0; r < 4; ++r) acc[nt][r] = fmaxf(acc[nt][r], 0.f);

    // fp32 projection: p[t][reg] = sum_col relu(S)[row][col] * Wlin[t][col]
    float p[8][4];
    #pragma unroll
    for (int tt = 0; tt < 8; ++tt) {
        float wl[8];
        #pragma unroll
        for (int nt = 0; nt < 8; ++nt) wl[nt] = WlinL[tt * F + nt * 16 + sl];
        #pragma unroll
        for (int r = 0; r < 4; ++r) {
            float s = 0.f;
            #pragma unroll
            for (int nt = 0; nt < 8; ++nt) s += acc[nt][r] * wl[nt];
            p[tt][r] = s;
        }
    }
    #pragma unroll
    for (int tt = 0; tt < 8; ++tt)
        #pragma unroll
        for (int r = 0; r < 4; ++r) {
            float v = p[tt][r];
            v += __shfl_xor(v, 1, 64); v += __shfl_xor(v, 2, 64);
            v += __shfl_xor(v, 4, 64); v += __shfl_xor(v, 8, 64);
            p[tt][r] = v;
        }
    if (sl == 0) {
        #pragma unroll
        for (int r = 0; r < 4; ++r) {
            int row = row0 + wave * 16 + q * 4 + r;
            if (row < N) {
                #pragma unroll
                for (int tt = 0; tt < 8; ++tt)
                    out[(size_t)row * 8 + tt] = p[tt][r] + blin[tt];
            }
        }
    }
}

// ---------- launch ----------
extern "C" void kernel_launch(void* const* d_in, const int* in_sizes, int n_in,
                              void* d_out, int out_size, void* d_ws, size_t ws_size,
                              hipStream_t stream) {
    const float* x    = (const float*)d_in[0];
    const int*   ei   = (const int*)d_in[1];
    const float* ew   = (const float*)d_in[2];
    const float* W0   = (const float*)d_in[3];
    const float* Wih  = (const float*)d_in[4];
    const float* Whh  = (const float*)d_in[5];
    const float* bih  = (const float*)d_in[6];
    const float* bhh  = (const float*)d_in[7];
    const float* Wlin = (const float*)d_in[8];
    const float* blin = (const float*)d_in[9];
    int N = in_sizes[0] / F;   // 50000
    int E = in_sizes[1] / 2;   // 800000
    float* outp = (float*)d_out;

    int nblk = (N + 255) / 256;
    int cntBlocks = (E + 255) / 256;
    int M = N * 64;

    char* wsb = (char*)d_ws;
    size_t cur = 0;
    auto alloc = [&](size_t sz) -> void* {
        void* p = wsb + cur;
        cur = (cur + sz + 255) & ~(size_t)255;
        return p;
    };
    unsigned long long* packed = (unsigned long long*)alloc((size_t)N * 8);
    float* dinv = (float*)alloc((size_t)N * 4);
    int*   off  = (int*)  alloc((size_t)(N + 1) * 4);
    int*   bsum = (int*)  alloc((size_t)nblk * 4);
    int*   flag = (int*)  alloc(256);
    int*   pos  = (int*)  alloc((size_t)E * 4);
    int2*  ep   = (int2*) alloc((size_t)E * 8);
    unsigned short* Wth = (unsigned short*)alloc((size_t)F * F * 2);
    unsigned short* Wtl = (unsigned short*)alloc((size_t)F * F * 2);
    unsigned int* xs    = (unsigned int*)alloc((size_t)N * 64 * 4);
    (void)ws_size; (void)n_in; (void)out_size;

    hipLaunchKernelGGL(k_init, dim3(nblk), dim3(256), 0, stream, packed, flag, ei, N);
    hipLaunchKernelGGL(k_count_evolve, dim3(cntBlocks + F), dim3(256), 0, stream,
                       ei, ew, packed, pos, flag, E, cntBlocks,
                       W0, Wih, Whh, bih, bhh, Wth, Wtl);
    {
        void* args[] = { (void*)&packed, (void*)&bsum, (void*)&off, (void*)&dinv,
                         (void*)&N, (void*)&E, (void*)&nblk };
        hipLaunchCooperativeKernel((void*)k_scan, dim3(nblk), dim3(256), args, 0, stream);
    }
    hipLaunchKernelGGL(k_place_cast, dim3(cntBlocks + (M + 255) / 256), dim3(256), 0, stream,
                       ei, ew, off, pos, ep, flag, E, cntBlocks,
                       (const float2*)x, dinv, xs, M);
    hipLaunchKernelGGL(k_agg_gemm, dim3((N + 63) / 64), dim3(256), 0, stream,
                       (const uint4*)xs, off, ep, dinv, Wth, Wtl, Wlin, blin, outp, N);
}

// Round 3
// 249.868 us; speedup vs baseline: 1.3950x; 1.3950x over previous
//
#include <hip/hip_runtime.h>
#include <math.h>

#define F 128
#define FIX_SCALE 16777216.0f          // 2^24
#define FIX_INV   (1.0f / 16777216.0f)
#define CNT_SHIFT 40
#define DEG_MASK  ((1ULL << 40) - 1)

using bf16x8 = __attribute__((ext_vector_type(8))) short;
using f32x4  = __attribute__((ext_vector_type(4))) float;

// ---------- helpers ----------
__device__ inline int read_idx(const int* ei, long long elem, int i64) {
    return i64 ? (int)((const long long*)ei)[elem] : ei[elem];
}
__device__ inline unsigned int f2bf_rn(float f) {   // fp32 -> bf16 bits, round-nearest-even
    unsigned int b = __float_as_uint(f);
    return (b + 0x7FFFu + ((b >> 16) & 1u)) >> 16;
}
__device__ inline float bflo(unsigned int u) { return __uint_as_float(u << 16); }
__device__ inline float bfhi(unsigned int u) { return __uint_as_float(u & 0xFFFF0000u); }

__device__ inline void acc8(float* acc, float wt, uint4 v) {
    acc[0] += wt * bflo(v.x); acc[1] += wt * bfhi(v.x);
    acc[2] += wt * bflo(v.y); acc[3] += wt * bfhi(v.y);
    acc[4] += wt * bflo(v.z); acc[5] += wt * bfhi(v.z);
    acc[6] += wt * bflo(v.w); acc[7] += wt * bfhi(v.w);
}

// ---------- K1: zero packed counters, detect index dtype ----------
__global__ void k_init(unsigned long long* packed, int* flag, const int* ei, int N) {
    int i = blockIdx.x * blockDim.x + threadIdx.x;
    if (i < N) packed[i] = 0ULL;
    if (i == 0) {
        int i64 = 1;
        for (int j = 0; j < 32; ++j) if (ei[2 * j + 1] != 0) { i64 = 0; break; }
        *flag = i64;
    }
}

// ---------- K2: count+deg atomics (blocks [0,cntBlocks)) + GRU evolve (blocks [cntBlocks,cntBlocks+F)) ----------
__global__ __launch_bounds__(256) void k_count_evolve(
        const int* __restrict__ ei, const float* __restrict__ ew,
        unsigned long long* __restrict__ packed, int* __restrict__ pos,
        const int* __restrict__ flag, int E, int cntBlocks,
        const float* __restrict__ W0, const float* __restrict__ Wih,
        const float* __restrict__ Whh, const float* __restrict__ bih,
        const float* __restrict__ bhh,
        unsigned short* __restrict__ Wth, unsigned short* __restrict__ Wtl) {
    __shared__ __align__(16) float w0row[F];
    if ((int)blockIdx.x < cntBlocks) {
        int e = blockIdx.x * 256 + threadIdx.x;
        if (e >= E) return;
        int i64 = *flag;
        int c = read_idx(ei, (long long)E + e, i64);
        unsigned long long u = (1ULL << CNT_SHIFT) |
                               (unsigned long long)(ew[e] * FIX_SCALE + 0.5f);
        unsigned long long old = atomicAdd(&packed[c], u);
        pos[e] = (int)(old >> CNT_SHIFT);
        return;
    }
    // ---- evolve path: one block per row i of W0; Wt[n][k] split-bf16 ----
    int i = blockIdx.x - cntBlocks;   // k index (row of W)
    int j = threadIdx.x;              // n index (col of W)
    if (j < F) w0row[j] = W0[i * F + j];
    __syncthreads();
    if (j >= F) return;
    float air = 0, aiz = 0, ain = 0, ahr = 0, ahz = 0, ahn = 0;
    const float* ir_p = Wih + (size_t)j * F;
    const float* iz_p = Wih + (size_t)(j + F) * F;
    const float* in_p = Wih + (size_t)(j + 2 * F) * F;
    const float* hr_p = Whh + (size_t)j * F;
    const float* hz_p = Whh + (size_t)(j + F) * F;
    const float* hn_p = Whh + (size_t)(j + 2 * F) * F;
    for (int k = 0; k < F; k += 4) {
        float4 w0 = *(const float4*)&w0row[k];
        float4 a;
        a = *(const float4*)&ir_p[k]; air += w0.x*a.x + w0.y*a.y + w0.z*a.z + w0.w*a.w;
        a = *(const float4*)&iz_p[k]; aiz += w0.x*a.x + w0.y*a.y + w0.z*a.z + w0.w*a.w;
        a = *(const float4*)&in_p[k]; ain += w0.x*a.x + w0.y*a.y + w0.z*a.z + w0.w*a.w;
        a = *(const float4*)&hr_p[k]; ahr += w0.x*a.x + w0.y*a.y + w0.z*a.z + w0.w*a.w;
        a = *(const float4*)&hz_p[k]; ahz += w0.x*a.x + w0.y*a.y + w0.z*a.z + w0.w*a.w;
        a = *(const float4*)&hn_p[k]; ahn += w0.x*a.x + w0.y*a.y + w0.z*a.z + w0.w*a.w;
    }
    air += bih[j];         ahr += bhh[j];
    aiz += bih[j + F];     ahz += bhh[j + F];
    ain += bih[j + 2*F];   ahn += bhh[j + 2*F];
    float r = 1.0f / (1.0f + expf(-(air + ahr)));
    float z = 1.0f / (1.0f + expf(-(aiz + ahz)));
    float n = tanhf(ain + r * ahn);
    float w = (1.0f - z) * n + z * w0row[j];
    unsigned int hb = f2bf_rn(w);
    float whi = __uint_as_float(hb << 16);
    unsigned int lb = f2bf_rn(w - whi);
    Wth[j * F + i] = (unsigned short)hb;
    Wtl[j * F + i] = (unsigned short)lb;
}

// ---------- K3a: per-block sums of cnt ----------
__global__ void k_bsum(const unsigned long long* __restrict__ packed,
                       int* __restrict__ bsum, int N) {
    __shared__ int s[4];
    int i = blockIdx.x * 256 + threadIdx.x;
    int v = (i < N) ? (int)(packed[i] >> CNT_SHIFT) : 0;
    #pragma unroll
    for (int o = 1; o < 64; o <<= 1) v += __shfl_xor(v, o, 64);
    if ((threadIdx.x & 63) == 0) s[threadIdx.x >> 6] = v;
    __syncthreads();
    if (threadIdx.x == 0) bsum[blockIdx.x] = s[0] + s[1] + s[2] + s[3];
}

// ---------- K3b: exclusive scan of bsum (nblk ~ 196), one block ----------
__global__ void k_bscan(int* bsum, int nb) {
    __shared__ int sdata[1024];
    int tid = threadIdx.x;
    int run = 0;
    for (int base = 0; base < nb; base += 1024) {
        int i = base + tid;
        int v = (i < nb) ? bsum[i] : 0;
        sdata[tid] = v;
        __syncthreads();
        #pragma unroll
        for (int s = 1; s < 1024; s <<= 1) {
            int add = (tid >= s) ? sdata[tid - s] : 0;
            __syncthreads();
            sdata[tid] += add;
            __syncthreads();
        }
        if (i < nb) bsum[i] = run + sdata[tid] - v;  // exclusive
        run += sdata[1023];
        __syncthreads();
    }
}

// ---------- K3c: off = exclusive CSR offsets; dinv = rsqrt(1 + deg) ----------
__global__ void k_offs(const unsigned long long* __restrict__ packed,
                       const int* __restrict__ bsum,
                       int* __restrict__ off, float* __restrict__ dinv, int N, int E) {
    __shared__ int sdata[256];
    int t = threadIdx.x;
    int i = blockIdx.x * 256 + t;
    unsigned long long p = (i < N) ? packed[i] : 0ULL;
    int v = (int)(p >> CNT_SHIFT);
    sdata[t] = v;
    __syncthreads();
    #pragma unroll
    for (int s = 1; s < 256; s <<= 1) {
        int add = (t >= s) ? sdata[t - s] : 0;
        __syncthreads();
        sdata[t] += add;
        __syncthreads();
    }
    if (i < N) {
        off[i] = bsum[blockIdx.x] + sdata[t] - v;  // exclusive
        float deg = 1.0f + (float)(p & DEG_MASK) * FIX_INV;  // +1 self-loop
        dinv[i] = rsqrtf(deg);
        if (i == N - 1) off[N] = E;
    }
}

// ---------- K4: edge placement (blocks [0,placeBlocks)) + xs cast (rest) ----------
__global__ __launch_bounds__(256) void k_place_cast(
        const int* __restrict__ ei, const float* __restrict__ ew,
        const int* __restrict__ off, const int* __restrict__ pos,
        int2* __restrict__ ep, const int* __restrict__ flag, int E, int placeBlocks,
        const float2* __restrict__ x2, const float* __restrict__ dinv,
        unsigned int* __restrict__ xs, int M) {
    if ((int)blockIdx.x < placeBlocks) {
        int e = blockIdx.x * 256 + threadIdx.x;
        if (e >= E) return;
        int i64 = *flag;
        int r = read_idx(ei, e, i64);
        int c = read_idx(ei, (long long)E + e, i64);
        ep[off[c] + pos[e]] = make_int2(r, __float_as_int(ew[e]));
    } else {
        int id = ((int)blockIdx.x - placeBlocks) * 256 + threadIdx.x;
        if (id >= M) return;
        float di = dinv[id >> 6];
        float2 v = x2[id];
        xs[id] = f2bf_rn(di * v.x) | (f2bf_rn(di * v.y) << 16);
    }
}

// ---------- K5: aggregation: hagg[c] = bf16( dinv[c] * (xs[c] + sum ew*xs[r]) ) ----------
// One node per wave; 16 edges/iteration (4 per 16-lane group), branchless tail via
// index clamp + zero weight so all 4 gathers issue unconditionally (deep MLP).
__global__ __launch_bounds__(256) void k_agg2(const uint4* __restrict__ xs4,
                                              const int* __restrict__ off,
                                              const int2* __restrict__ ep,
                                              const float* __restrict__ dinv,
                                              uint4* __restrict__ hagg4, int N) {
    int wave = threadIdx.x >> 6, lane = threadIdx.x & 63;
    int c = blockIdx.x * 4 + wave;
    if (c >= N) return;
    int g = lane >> 4, sl = lane & 15;
    int start = off[c], end = off[c + 1];
    float di = dinv[c];
    float a0[8] = {0,0,0,0,0,0,0,0}, a1[8] = {0,0,0,0,0,0,0,0};
    if (g == 0) {   // self-loop (raw weight 1)
        uint4 v = xs4[(size_t)c * 16 + sl];
        a0[0] = bflo(v.x); a0[1] = bfhi(v.x);
        a0[2] = bflo(v.y); a0[3] = bfhi(v.y);
        a0[4] = bflo(v.z); a0[5] = bfhi(v.z);
        a0[6] = bflo(v.w); a0[7] = bfhi(v.w);
    }
    int last = end - 1;
    for (int k = start; k < end; k += 16) {
        int iA = k + g, iB = k + g + 4, iC = k + g + 8, iD = k + g + 12;
        int2 eA = ep[min(iA, last)];
        int2 eB = ep[min(iB, last)];
        int2 eC = ep[min(iC, last)];
        int2 eD = ep[min(iD, last)];
        uint4 vA = xs4[(size_t)eA.x * 16 + sl];
        uint4 vB = xs4[(size_t)eB.x * 16 + sl];
        uint4 vC = xs4[(size_t)eC.x * 16 + sl];
        uint4 vD = xs4[(size_t)eD.x * 16 + sl];
        float wA = (iA <= last) ? __int_as_float(eA.y) : 0.f;
        float wB = (iB <= last) ? __int_as_float(eB.y) : 0.f;
        float wC = (iC <= last) ? __int_as_float(eC.y) : 0.f;
        float wD = (iD <= last) ? __int_as_float(eD.y) : 0.f;
        acc8(a0, wA, vA);
        acc8(a1, wB, vB);
        acc8(a0, wC, vC);
        acc8(a1, wD, vD);
    }
    #pragma unroll
    for (int f = 0; f < 8; ++f) {
        float v = a0[f] + a1[f];
        v += __shfl_xor(v, 16, 64);
        v += __shfl_xor(v, 32, 64);
        a0[f] = v;
    }
    if (lane < 16) {
        uint4 o;
        o.x = f2bf_rn(di * a0[0]) | (f2bf_rn(di * a0[1]) << 16);
        o.y = f2bf_rn(di * a0[2]) | (f2bf_rn(di * a0[3]) << 16);
        o.z = f2bf_rn(di * a0[4]) | (f2bf_rn(di * a0[5]) << 16);
        o.w = f2bf_rn(di * a0[6]) | (f2bf_rn(di * a0[7]) << 16);
        hagg4[(size_t)c * 16 + lane] = o;
    }
}

// ---------- K6: out = relu(hagg @ W) @ Wlin^T + blin  (MFMA, split-bf16 W) ----------
__global__ __launch_bounds__(256) void k_gemm(const uint4* __restrict__ hagg4,
                                              const unsigned short* __restrict__ Wth,
                                              const unsigned short* __restrict__ Wtl,
                                              const float* __restrict__ Wlin,
                                              const float* __restrict__ blin,
                                              float* __restrict__ out, int N) {
    __shared__ __align__(16) unsigned int At[64 * 68];  // 64 rows bf16x128, stride padded 68 uints
    __shared__ __align__(16) float WlinL[8 * F];
    int t = threadIdx.x;
    int row0 = blockIdx.x * 64;
    #pragma unroll
    for (int it = 0; it < 4; ++it) {
        int idx = it * 256 + t;          // 1024 uint4 slots
        int rr = idx >> 4, c4 = idx & 15;
        uint4 v = make_uint4(0u, 0u, 0u, 0u);
        if (row0 + rr < N) v = hagg4[(size_t)(row0 + rr) * 16 + c4];
        *(uint4*)&At[rr * 68 + c4 * 4] = v;
    }
    *(float4*)&WlinL[t * 4] = *(const float4*)&Wlin[t * 4];   // 1024 floats
    __syncthreads();

    int wave = t >> 6, lane = t & 63;
    int sl = lane & 15, q = lane >> 4;
    const unsigned short* Ash = (const unsigned short*)At;
    int mrow = wave * 16 + sl;           // A-row within tile (m = lane&15)

    f32x4 acc[8];
    #pragma unroll
    for (int nt = 0; nt < 8; ++nt) acc[nt] = (f32x4){0.f, 0.f, 0.f, 0.f};
    #pragma unroll
    for (int ko = 0; ko < 4; ++ko) {
        bf16x8 a = *(const bf16x8*)&Ash[mrow * 136 + ko * 32 + q * 8];
        #pragma unroll
        for (int nt = 0; nt < 8; ++nt) {
            int boff = (nt * 16 + sl) * F + ko * 32 + q * 8;
            bf16x8 bh = *(const bf16x8*)&Wth[boff];
            bf16x8 bl = *(const bf16x8*)&Wtl[boff];
            acc[nt] = __builtin_amdgcn_mfma_f32_16x16x32_bf16(a, bh, acc[nt], 0, 0, 0);
            acc[nt] = __builtin_amdgcn_mfma_f32_16x16x32_bf16(a, bl, acc[nt], 0, 0, 0);
        }
    }
    // relu (C layout: row = q*4+reg, col = nt*16+sl)
    #pragma unroll
    for (int nt = 0; nt < 8; ++nt)
        #pragma unroll
        for (int r = 0; r < 4; ++r) acc[nt][r] = fmaxf(acc[nt][r], 0.f);

    // fp32 projection: p[t][reg] = sum_col relu(S)[row][col] * Wlin[t][col]
    float p[8][4];
    #pragma unroll
    for (int tt = 0; tt < 8; ++tt) {
        float wl[8];
        #pragma unroll
        for (int nt = 0; nt < 8; ++nt) wl[nt] = WlinL[tt * F + nt * 16 + sl];
        #pragma unroll
        for (int r = 0; r < 4; ++r) {
            float s = 0.f;
            #pragma unroll
            for (int nt = 0; nt < 8; ++nt) s += acc[nt][r] * wl[nt];
            p[tt][r] = s;
        }
    }
    #pragma unroll
    for (int tt = 0; tt < 8; ++tt)
        #pragma unroll
        for (int r = 0; r < 4; ++r) {
            float v = p[tt][r];
            v += __shfl_xor(v, 1, 64); v += __shfl_xor(v, 2, 64);
            v += __shfl_xor(v, 4, 64); v += __shfl_xor(v, 8, 64);
            p[tt][r] = v;
        }
    if (sl == 0) {
        #pragma unroll
        for (int r = 0; r < 4; ++r) {
            int row = row0 + wave * 16 + q * 4 + r;
            if (row < N) {
                #pragma unroll
                for (int tt = 0; tt < 8; ++tt)
                    out[(size_t)row * 8 + tt] = p[tt][r] + blin[tt];
            }
        }
    }
}

// ---------- launch ----------
extern "C" void kernel_launch(void* const* d_in, const int* in_sizes, int n_in,
                              void* d_out, int out_size, void* d_ws, size_t ws_size,
                              hipStream_t stream) {
    const float* x    = (const float*)d_in[0];
    const int*   ei   = (const int*)d_in[1];
    const float* ew   = (const float*)d_in[2];
    const float* W0   = (const float*)d_in[3];
    const float* Wih  = (const float*)d_in[4];
    const float* Whh  = (const float*)d_in[5];
    const float* bih  = (const float*)d_in[6];
    const float* bhh  = (const float*)d_in[7];
    const float* Wlin = (const float*)d_in[8];
    const float* blin = (const float*)d_in[9];
    int N = in_sizes[0] / F;   // 50000
    int E = in_sizes[1] / 2;   // 800000
    float* outp = (float*)d_out;

    int nblk = (N + 255) / 256;
    int cntBlocks = (E + 255) / 256;
    int M = N * 64;

    char* wsb = (char*)d_ws;
    size_t cur = 0;
    auto alloc = [&](size_t sz) -> void* {
        void* p = wsb + cur;
        cur = (cur + sz + 255) & ~(size_t)255;
        return p;
    };
    unsigned long long* packed = (unsigned long long*)alloc((size_t)N * 8);
    float* dinv = (float*)alloc((size_t)N * 4);
    int*   off  = (int*)  alloc((size_t)(N + 1) * 4);
    int*   bsum = (int*)  alloc((size_t)nblk * 4);
    int*   flag = (int*)  alloc(256);
    int*   pos  = (int*)  alloc((size_t)E * 4);
    int2*  ep   = (int2*) alloc((size_t)E * 8);
    unsigned short* Wth = (unsigned short*)alloc((size_t)F * F * 2);
    unsigned short* Wtl = (unsigned short*)alloc((size_t)F * F * 2);
    unsigned int* xs    = (unsigned int*)alloc((size_t)N * 64 * 4);
    unsigned int* hagg  = (unsigned int*)alloc((size_t)N * 64 * 4);
    (void)ws_size; (void)n_in; (void)out_size;

    hipLaunchKernelGGL(k_init, dim3(nblk), dim3(256), 0, stream, packed, flag, ei, N);
    hipLaunchKernelGGL(k_count_evolve, dim3(cntBlocks + F), dim3(256), 0, stream,
                       ei, ew, packed, pos, flag, E, cntBlocks,
                       W0, Wih, Whh, bih, bhh, Wth, Wtl);
    hipLaunchKernelGGL(k_bsum,  dim3(nblk), dim3(256),  0, stream, packed, bsum, N);
    hipLaunchKernelGGL(k_bscan, dim3(1),    dim3(1024), 0, stream, bsum, nblk);
    hipLaunchKernelGGL(k_offs,  dim3(nblk), dim3(256),  0, stream, packed, bsum, off, dinv, N, E);
    hipLaunchKernelGGL(k_place_cast, dim3(cntBlocks + (M + 255) / 256), dim3(256), 0, stream,
                       ei, ew, off, pos, ep, flag, E, cntBlocks,
                       (const float2*)x, dinv, xs, M);
    hipLaunchKernelGGL(k_agg2, dim3((N + 3) / 4), dim3(256), 0, stream,
                       (const uint4*)xs, off, ep, dinv, (uint4*)hagg, N);
    hipLaunchKernelGGL(k_gemm, dim3((N + 63) / 64), dim3(256), 0, stream,
                       (const uint4*)hagg, Wth, Wtl, Wlin, blin, outp, N);
}

// Round 4
// 219.587 us; speedup vs baseline: 1.5873x; 1.1379x over previous
//
#include <hip/hip_runtime.h>
#include <math.h>

#define F 128
#define FIX_SCALE 16777216.0f          // 2^24
#define FIX_INV   (1.0f / 16777216.0f)
#define CNT_SHIFT 40
#define DEG_MASK  ((1ULL << 40) - 1)
#define EVB 256                        // evolve blocks at front of count grid

using bf16x8 = __attribute__((ext_vector_type(8))) short;
using f32x4  = __attribute__((ext_vector_type(4))) float;

// ---------- helpers ----------
__device__ inline int read_idx(const int* ei, long long elem, int i64) {
    return i64 ? (int)((const long long*)ei)[elem] : ei[elem];
}
__device__ inline unsigned int f2bf_rn(float f) {   // fp32 -> bf16 bits, round-nearest-even
    unsigned int b = __float_as_uint(f);
    return (b + 0x7FFFu + ((b >> 16) & 1u)) >> 16;
}
__device__ inline float bflo(unsigned int u) { return __uint_as_float(u << 16); }
__device__ inline float bfhi(unsigned int u) { return __uint_as_float(u & 0xFFFF0000u); }

__device__ inline void acc8(float* acc, float wt, uint4 v) {
    acc[0] += wt * bflo(v.x); acc[1] += wt * bfhi(v.x);
    acc[2] += wt * bflo(v.y); acc[3] += wt * bfhi(v.y);
    acc[4] += wt * bflo(v.z); acc[5] += wt * bfhi(v.z);
    acc[6] += wt * bflo(v.w); acc[7] += wt * bfhi(v.w);
}

// ---------- K1: zero 8 privatized counter copies, detect index dtype ----------
__global__ void k_init(unsigned long long* packed8, int* flag, const int* ei, int M8) {
    int i = blockIdx.x * blockDim.x + threadIdx.x;
    if (i < M8) packed8[i] = 0ULL;
    if (i == 0) {
        int i64 = 1;
        for (int j = 0; j < 32; ++j) if (ei[2 * j + 1] != 0) { i64 = 0; break; }
        *flag = i64;
    }
}

// ---------- K2: GRU evolve (blocks [0,EVB)) + XCD-privatized count atomics (rest) ----------
// Evolve: split-K over 4 lane-groups (16 (i,j) pairs x 4 K-slices per wave), shuffle-reduce.
// Count: atomic into copy (blockIdx&7) -> line stays in home-XCD L2; pos = (copy<<24)|localpos.
__global__ __launch_bounds__(256) void k_count_evolve(
        const int* __restrict__ ei, const float* __restrict__ ew,
        unsigned long long* __restrict__ packed8, int* __restrict__ pos,
        const int* __restrict__ flag, int E, int N,
        const float* __restrict__ W0, const float* __restrict__ Wih,
        const float* __restrict__ Whh, const float* __restrict__ bih,
        const float* __restrict__ bhh,
        unsigned short* __restrict__ Wth, unsigned short* __restrict__ Wtl) {
    int wave = threadIdx.x >> 6, lane = threadIdx.x & 63;
    if ((int)blockIdx.x >= EVB) {
        int e = ((int)blockIdx.x - EVB) * 256 + threadIdx.x;
        if (e >= E) return;
        int i64 = *flag;
        int c = read_idx(ei, (long long)E + e, i64);
        int copy = blockIdx.x & 7;
        unsigned long long u = (1ULL << CNT_SHIFT) |
                               (unsigned long long)(ew[e] * FIX_SCALE + 0.5f);
        unsigned long long old = atomicAdd(&packed8[(size_t)copy * N + c], u);
        pos[e] = (int)(((unsigned int)(old >> CNT_SHIFT)) | ((unsigned int)copy << 24));
        return;
    }
    // ---- evolve: wave gw handles pairs [gw*16, gw*16+16), lane = (slice<<4)|lp ----
    int gw = (int)blockIdx.x * 4 + wave;          // 0..1023
    int pairBase = gw * 16;
    int i = pairBase >> 7;                        // row of W0
    int jb = pairBase & 127;
    int lp = lane & 15, sl = lane >> 4;           // pair-in-wave, K-slice
    int j = jb + lp;                              // col of W
    const float* w0p = W0 + (size_t)i * F;
    const float* pir = Wih + (size_t)j * F;
    const float* piz = Wih + (size_t)(j + F) * F;
    const float* pin = Wih + (size_t)(j + 2 * F) * F;
    const float* phr = Whh + (size_t)j * F;
    const float* phz = Whh + (size_t)(j + F) * F;
    const float* phn = Whh + (size_t)(j + 2 * F) * F;
    float air = 0, aiz = 0, ain = 0, ahr = 0, ahz = 0, ahn = 0;
    int k0 = sl * 32;
    #pragma unroll
    for (int kk = 0; kk < 32; kk += 4) {
        int k = k0 + kk;
        float4 w0 = *(const float4*)&w0p[k];
        float4 a;
        a = *(const float4*)&pir[k]; air += w0.x*a.x + w0.y*a.y + w0.z*a.z + w0.w*a.w;
        a = *(const float4*)&piz[k]; aiz += w0.x*a.x + w0.y*a.y + w0.z*a.z + w0.w*a.w;
        a = *(const float4*)&pin[k]; ain += w0.x*a.x + w0.y*a.y + w0.z*a.z + w0.w*a.w;
        a = *(const float4*)&phr[k]; ahr += w0.x*a.x + w0.y*a.y + w0.z*a.z + w0.w*a.w;
        a = *(const float4*)&phz[k]; ahz += w0.x*a.x + w0.y*a.y + w0.z*a.z + w0.w*a.w;
        a = *(const float4*)&phn[k]; ahn += w0.x*a.x + w0.y*a.y + w0.z*a.z + w0.w*a.w;
    }
    air += __shfl_xor(air, 16, 64); air += __shfl_xor(air, 32, 64);
    aiz += __shfl_xor(aiz, 16, 64); aiz += __shfl_xor(aiz, 32, 64);
    ain += __shfl_xor(ain, 16, 64); ain += __shfl_xor(ain, 32, 64);
    ahr += __shfl_xor(ahr, 16, 64); ahr += __shfl_xor(ahr, 32, 64);
    ahz += __shfl_xor(ahz, 16, 64); ahz += __shfl_xor(ahz, 32, 64);
    ahn += __shfl_xor(ahn, 16, 64); ahn += __shfl_xor(ahn, 32, 64);
    if (sl == 0) {
        air += bih[j];          ahr += bhh[j];
        aiz += bih[j + F];      ahz += bhh[j + F];
        ain += bih[j + 2 * F];  ahn += bhh[j + 2 * F];
        float r = 1.0f / (1.0f + expf(-(air + ahr)));
        float z = 1.0f / (1.0f + expf(-(aiz + ahz)));
        float n = tanhf(ain + r * ahn);
        float w = (1.0f - z) * n + z * w0p[j];
        unsigned int hb = f2bf_rn(w);
        float whi = __uint_as_float(hb << 16);
        unsigned int lb = f2bf_rn(w - whi);
        Wth[j * F + i] = (unsigned short)hb;
        Wtl[j * F + i] = (unsigned short)lb;
    }
}

// ---------- K3a: per-block sums of cnt (summed over 8 copies) ----------
__global__ void k_bsum(const unsigned long long* __restrict__ packed8,
                       int* __restrict__ bsum, int N) {
    __shared__ int s[4];
    int i = blockIdx.x * 256 + threadIdx.x;
    int v = 0;
    if (i < N) {
        #pragma unroll
        for (int k = 0; k < 8; ++k)
            v += (int)(packed8[(size_t)k * N + i] >> CNT_SHIFT);
    }
    #pragma unroll
    for (int o = 1; o < 64; o <<= 1) v += __shfl_xor(v, o, 64);
    if ((threadIdx.x & 63) == 0) s[threadIdx.x >> 6] = v;
    __syncthreads();
    if (threadIdx.x == 0) bsum[blockIdx.x] = s[0] + s[1] + s[2] + s[3];
}

// ---------- K3b: exclusive scan of bsum (nblk ~ 196), one block ----------
__global__ void k_bscan(int* bsum, int nb) {
    __shared__ int sdata[1024];
    int tid = threadIdx.x;
    int run = 0;
    for (int base = 0; base < nb; base += 1024) {
        int i = base + tid;
        int v = (i < nb) ? bsum[i] : 0;
        sdata[tid] = v;
        __syncthreads();
        #pragma unroll
        for (int s = 1; s < 1024; s <<= 1) {
            int add = (tid >= s) ? sdata[tid - s] : 0;
            __syncthreads();
            sdata[tid] += add;
            __syncthreads();
        }
        if (i < nb) bsum[i] = run + sdata[tid] - v;  // exclusive
        run += sdata[1023];
        __syncthreads();
    }
}

// ---------- K3c: off = exclusive CSR offsets; per-copy bases; dinv ----------
__global__ void k_offs(const unsigned long long* __restrict__ packed8,
                       const int* __restrict__ bsum,
                       int* __restrict__ off, int* __restrict__ copyBase,
                       float* __restrict__ dinv, int N, int E) {
    __shared__ int sdata[256];
    int t = threadIdx.x;
    int i = blockIdx.x * 256 + t;
    int v = 0;
    unsigned long long dsum = 0;
    int cb[8];
    if (i < N) {
        int run = 0;
        #pragma unroll
        for (int k = 0; k < 8; ++k) {
            unsigned long long p = packed8[(size_t)k * N + i];
            cb[k] = run;
            run += (int)(p >> CNT_SHIFT);
            dsum += (p & DEG_MASK);
        }
        v = run;
        #pragma unroll
        for (int k = 0; k < 8; ++k) copyBase[(size_t)i * 8 + k] = cb[k];
    }
    sdata[t] = v;
    __syncthreads();
    #pragma unroll
    for (int s = 1; s < 256; s <<= 1) {
        int add = (t >= s) ? sdata[t - s] : 0;
        __syncthreads();
        sdata[t] += add;
        __syncthreads();
    }
    if (i < N) {
        off[i] = bsum[blockIdx.x] + sdata[t] - v;  // exclusive
        float deg = 1.0f + (float)dsum * FIX_INV;  // +1 self-loop
        dinv[i] = rsqrtf(deg);
        if (i == N - 1) off[N] = E;
    }
}

// ---------- K4: edge placement (blocks [0,placeBlocks)) + xs cast (rest) ----------
__global__ __launch_bounds__(256) void k_place_cast(
        const int* __restrict__ ei, const float* __restrict__ ew,
        const int* __restrict__ off, const int* __restrict__ copyBase,
        const int* __restrict__ pos,
        int2* __restrict__ ep, const int* __restrict__ flag, int E, int placeBlocks,
        const float2* __restrict__ x2, const float* __restrict__ dinv,
        unsigned int* __restrict__ xs, int M) {
    if ((int)blockIdx.x < placeBlocks) {
        int e = blockIdx.x * 256 + threadIdx.x;
        if (e >= E) return;
        int i64 = *flag;
        int r = read_idx(ei, e, i64);
        int c = read_idx(ei, (long long)E + e, i64);
        int pe = pos[e];
        int slot = off[c] + copyBase[(size_t)c * 8 + (pe >> 24)] + (pe & 0xFFFFFF);
        ep[slot] = make_int2(r, __float_as_int(ew[e]));
    } else {
        int id = ((int)blockIdx.x - placeBlocks) * 256 + threadIdx.x;
        if (id >= M) return;
        float di = dinv[id >> 6];
        float2 v = x2[id];
        xs[id] = f2bf_rn(di * v.x) | (f2bf_rn(di * v.y) << 16);
    }
}

// ---------- K5: aggregation: hagg[c] = bf16( dinv[c] * (xs[c] + sum ew*xs[r]) ) ----------
// One node per wave; 16 edges/iteration (4 per 16-lane group), branchless tail via
// index clamp + zero weight so all 4 gathers issue unconditionally (deep MLP).
__global__ __launch_bounds__(256) void k_agg2(const uint4* __restrict__ xs4,
                                              const int* __restrict__ off,
                                              const int2* __restrict__ ep,
                                              const float* __restrict__ dinv,
                                              uint4* __restrict__ hagg4, int N) {
    int wave = threadIdx.x >> 6, lane = threadIdx.x & 63;
    int c = blockIdx.x * 4 + wave;
    if (c >= N) return;
    int g = lane >> 4, sl = lane & 15;
    int start = off[c], end = off[c + 1];
    float di = dinv[c];
    float a0[8] = {0,0,0,0,0,0,0,0}, a1[8] = {0,0,0,0,0,0,0,0};
    if (g == 0) {   // self-loop (raw weight 1)
        uint4 v = xs4[(size_t)c * 16 + sl];
        a0[0] = bflo(v.x); a0[1] = bfhi(v.x);
        a0[2] = bflo(v.y); a0[3] = bfhi(v.y);
        a0[4] = bflo(v.z); a0[5] = bfhi(v.z);
        a0[6] = bflo(v.w); a0[7] = bfhi(v.w);
    }
    int last = end - 1;
    for (int k = start; k < end; k += 16) {
        int iA = k + g, iB = k + g + 4, iC = k + g + 8, iD = k + g + 12;
        int2 eA = ep[min(iA, last)];
        int2 eB = ep[min(iB, last)];
        int2 eC = ep[min(iC, last)];
        int2 eD = ep[min(iD, last)];
        uint4 vA = xs4[(size_t)eA.x * 16 + sl];
        uint4 vB = xs4[(size_t)eB.x * 16 + sl];
        uint4 vC = xs4[(size_t)eC.x * 16 + sl];
        uint4 vD = xs4[(size_t)eD.x * 16 + sl];
        float wA = (iA <= last) ? __int_as_float(eA.y) : 0.f;
        float wB = (iB <= last) ? __int_as_float(eB.y) : 0.f;
        float wC = (iC <= last) ? __int_as_float(eC.y) : 0.f;
        float wD = (iD <= last) ? __int_as_float(eD.y) : 0.f;
        acc8(a0, wA, vA);
        acc8(a1, wB, vB);
        acc8(a0, wC, vC);
        acc8(a1, wD, vD);
    }
    #pragma unroll
    for (int f = 0; f < 8; ++f) {
        float v = a0[f] + a1[f];
        v += __shfl_xor(v, 16, 64);
        v += __shfl_xor(v, 32, 64);
        a0[f] = v;
    }
    if (lane < 16) {
        uint4 o;
        o.x = f2bf_rn(di * a0[0]) | (f2bf_rn(di * a0[1]) << 16);
        o.y = f2bf_rn(di * a0[2]) | (f2bf_rn(di * a0[3]) << 16);
        o.z = f2bf_rn(di * a0[4]) | (f2bf_rn(di * a0[5]) << 16);
        o.w = f2bf_rn(di * a0[6]) | (f2bf_rn(di * a0[7]) << 16);
        hagg4[(size_t)c * 16 + lane] = o;
    }
}

// ---------- K6: out = relu(hagg @ W) @ Wlin^T + blin  (MFMA, split-bf16 W) ----------
__global__ __launch_bounds__(256) void k_gemm(const uint4* __restrict__ hagg4,
                                              const unsigned short* __restrict__ Wth,
                                              const unsigned short* __restrict__ Wtl,
                                              const float* __restrict__ Wlin,
                                              const float* __restrict__ blin,
                                              float* __restrict__ out, int N) {
    __shared__ __align__(16) unsigned int At[64 * 68];  // 64 rows bf16x128, stride padded 68 uints
    __shared__ __align__(16) float WlinL[8 * F];
    int t = threadIdx.x;
    int row0 = blockIdx.x * 64;
    #pragma unroll
    for (int it = 0; it < 4; ++it) {
        int idx = it * 256 + t;          // 1024 uint4 slots
        int rr = idx >> 4, c4 = idx & 15;
        uint4 v = make_uint4(0u, 0u, 0u, 0u);
        if (row0 + rr < N) v = hagg4[(size_t)(row0 + rr) * 16 + c4];
        *(uint4*)&At[rr * 68 + c4 * 4] = v;
    }
    *(float4*)&WlinL[t * 4] = *(const float4*)&Wlin[t * 4];   // 1024 floats
    __syncthreads();

    int wave = t >> 6, lane = t & 63;
    int sl = lane & 15, q = lane >> 4;
    const unsigned short* Ash = (const unsigned short*)At;
    int mrow = wave * 16 + sl;           // A-row within tile (m = lane&15)

    f32x4 acc[8];
    #pragma unroll
    for (int nt = 0; nt < 8; ++nt) acc[nt] = (f32x4){0.f, 0.f, 0.f, 0.f};
    #pragma unroll
    for (int ko = 0; ko < 4; ++ko) {
        bf16x8 a = *(const bf16x8*)&Ash[mrow * 136 + ko * 32 + q * 8];
        #pragma unroll
        for (int nt = 0; nt < 8; ++nt) {
            int boff = (nt * 16 + sl) * F + ko * 32 + q * 8;
            bf16x8 bh = *(const bf16x8*)&Wth[boff];
            bf16x8 bl = *(const bf16x8*)&Wtl[boff];
            acc[nt] = __builtin_amdgcn_mfma_f32_16x16x32_bf16(a, bh, acc[nt], 0, 0, 0);
            acc[nt] = __builtin_amdgcn_mfma_f32_16x16x32_bf16(a, bl, acc[nt], 0, 0, 0);
        }
    }
    // relu (C layout: row = q*4+reg, col = nt*16+sl)
    #pragma unroll
    for (int nt = 0; nt < 8; ++nt)
        #pragma unroll
        for (int r = 0; r < 4; ++r) acc[nt][r] = fmaxf(acc[nt][r], 0.f);

    // fp32 projection: p[t][reg] = sum_col relu(S)[row][col] * Wlin[t][col]
    float p[8][4];
    #pragma unroll
    for (int tt = 0; tt < 8; ++tt) {
        float wl[8];
        #pragma unroll
        for (int nt = 0; nt < 8; ++nt) wl[nt] = WlinL[tt * F + nt * 16 + sl];
        #pragma unroll
        for (int r = 0; r < 4; ++r) {
            float s = 0.f;
            #pragma unroll
            for (int nt = 0; nt < 8; ++nt) s += acc[nt][r] * wl[nt];
            p[tt][r] = s;
        }
    }
    #pragma unroll
    for (int tt = 0; tt < 8; ++tt)
        #pragma unroll
        for (int r = 0; r < 4; ++r) {
            float v = p[tt][r];
            v += __shfl_xor(v, 1, 64); v += __shfl_xor(v, 2, 64);
            v += __shfl_xor(v, 4, 64); v += __shfl_xor(v, 8, 64);
            p[tt][r] = v;
        }
    if (sl == 0) {
        #pragma unroll
        for (int r = 0; r < 4; ++r) {
            int row = row0 + wave * 16 + q * 4 + r;
            if (row < N) {
                #pragma unroll
                for (int tt = 0; tt < 8; ++tt)
                    out[(size_t)row * 8 + tt] = p[tt][r] + blin[tt];
            }
        }
    }
}

// ---------- launch ----------
extern "C" void kernel_launch(void* const* d_in, const int* in_sizes, int n_in,
                              void* d_out, int out_size, void* d_ws, size_t ws_size,
                              hipStream_t stream) {
    const float* x    = (const float*)d_in[0];
    const int*   ei   = (const int*)d_in[1];
    const float* ew   = (const float*)d_in[2];
    const float* W0   = (const float*)d_in[3];
    const float* Wih  = (const float*)d_in[4];
    const float* Whh  = (const float*)d_in[5];
    const float* bih  = (const float*)d_in[6];
    const float* bhh  = (const float*)d_in[7];
    const float* Wlin = (const float*)d_in[8];
    const float* blin = (const float*)d_in[9];
    int N = in_sizes[0] / F;   // 50000
    int E = in_sizes[1] / 2;   // 800000
    float* outp = (float*)d_out;

    int nblk = (N + 255) / 256;
    int cntBlocks = (E + 255) / 256;
    int M = N * 64;
    int M8 = N * 8;

    char* wsb = (char*)d_ws;
    size_t cur = 0;
    auto alloc = [&](size_t sz) -> void* {
        void* p = wsb + cur;
        cur = (cur + sz + 255) & ~(size_t)255;
        return p;
    };
    unsigned long long* packed8 = (unsigned long long*)alloc((size_t)M8 * 8);
    float* dinv = (float*)alloc((size_t)N * 4);
    int*   off  = (int*)  alloc((size_t)(N + 1) * 4);
    int*   bsum = (int*)  alloc((size_t)nblk * 4);
    int*   flag = (int*)  alloc(256);
    int*   pos  = (int*)  alloc((size_t)E * 4);
    int*   copyBase = (int*)alloc((size_t)N * 8 * 4);
    int2*  ep   = (int2*) alloc((size_t)E * 8);
    unsigned short* Wth = (unsigned short*)alloc((size_t)F * F * 2);
    unsigned short* Wtl = (unsigned short*)alloc((size_t)F * F * 2);
    unsigned int* xs    = (unsigned int*)alloc((size_t)N * 64 * 4);
    unsigned int* hagg  = (unsigned int*)alloc((size_t)N * 64 * 4);
    (void)ws_size; (void)n_in; (void)out_size;

    hipLaunchKernelGGL(k_init, dim3((M8 + 255) / 256), dim3(256), 0, stream, packed8, flag, ei, M8);
    hipLaunchKernelGGL(k_count_evolve, dim3(EVB + cntBlocks), dim3(256), 0, stream,
                       ei, ew, packed8, pos, flag, E, N,
                       W0, Wih, Whh, bih, bhh, Wth, Wtl);
    hipLaunchKernelGGL(k_bsum,  dim3(nblk), dim3(256),  0, stream, packed8, bsum, N);
    hipLaunchKernelGGL(k_bscan, dim3(1),    dim3(1024), 0, stream, bsum, nblk);
    hipLaunchKernelGGL(k_offs,  dim3(nblk), dim3(256),  0, stream, packed8, bsum, off, copyBase, dinv, N, E);
    hipLaunchKernelGGL(k_place_cast, dim3(cntBlocks + (M + 255) / 256), dim3(256), 0, stream,
                       ei, ew, off, copyBase, pos, ep, flag, E, cntBlocks,
                       (const float2*)x, dinv, xs, M);
    hipLaunchKernelGGL(k_agg2, dim3((N + 3) / 4), dim3(256), 0, stream,
                       (const uint4*)xs, off, ep, dinv, (uint4*)hagg, N);
    hipLaunchKernelGGL(k_gemm, dim3((N + 63) / 64), dim3(256), 0, stream,
                       (const uint4*)hagg, Wth, Wtl, Wlin, blin, outp, N);
}